// Round 1
// baseline (191.201 us; speedup 1.0000x reference)
//
#include <hip/hip_runtime.h>
#include <math.h>

// ImplicitPolygonInjector: B=4, C=128, H=W=64, S=4
// out[b][j][h*4+sy][w*4+sx] = (relu(hf[b,h,w,:] + hg[sy,sx,:] + b1) @ w2 + b2)[j] * gate[b,h,w]
//
// Block: 256 threads, handles one (b, h) and 16 consecutive w.
// Grid: 4*64*4 = 1024 blocks.
// LDS: hf[16][132] (padded), hgb[16][132], gate_s[16], hid[128][64] (f_tile/glds alias hid).

__global__ __launch_bounds__(256, 2) void ipi_kernel(
    const float* __restrict__ feat,     // (4,128,64,64)
    const float* __restrict__ gate_w1,  // (128,32)
    const float* __restrict__ gate_w2,  // (32,1)
    const float* __restrict__ gate_b2,  // (1,)
    const float* __restrict__ mlp_w1,   // (130,128)
    const float* __restrict__ mlp_b1,   // (128,)
    const float* __restrict__ mlp_w2,   // (128,128)
    const float* __restrict__ mlp_b2,   // (128,)
    float* __restrict__ out)            // (4,128,256,256)
{
    __shared__ float hf[16 * 132];
    __shared__ float hgb[16 * 132];
    __shared__ float gate_s[16];
    __shared__ float hid[128 * 64];
    float* f_tile = hid;          // [128][16], dead after stage 3
    float* glds   = hid + 2048;   // [16][32], dead after stage 2b

    const int t  = threadIdx.x;
    const int bx = blockIdx.x;
    const int w0 = (bx & 3) * 16;
    const int h  = (bx >> 2) & 63;
    const int b  = bx >> 8;

    // ---- stage 0: stage f tile (layout [c][w]) + hgb = h_g + b1 ----
    {
        const float* fbase = feat + ((size_t)(b * 128) * 64 + h) * 64 + w0;
        #pragma unroll
        for (int i = 0; i < 8; ++i) {
            int idx = t + i * 256;            // 2048 = 128c * 16w
            int c = idx >> 4, w = idx & 15;
            f_tile[c * 16 + w] = fbase[(size_t)c * 4096 + w];
        }
        #pragma unroll
        for (int i = 0; i < 8; ++i) {
            int idx = t + i * 256;            // 2048 = 16s * 128k
            int s = idx >> 7, k = idx & 127;
            float cx = -0.75f + 0.5f * (float)(s & 3);   // coords[sx]
            float cy = -0.75f + 0.5f * (float)(s >> 2);  // coords[sy]
            hgb[s * 132 + k] = cx * mlp_w1[128 * 128 + k]
                             + cy * mlp_w1[129 * 128 + k]
                             + mlp_b1[k];
        }
    }
    __syncthreads();

    // ---- stage 2a: gate hidden layer g = leaky(f @ gate_w1) ----
    {
        int jg = t & 31, wq = t >> 5;         // wq in 0..7, handles w=wq and w=wq+8
        float a0 = 0.f, a1 = 0.f;
        for (int c = 0; c < 128; ++c) {
            float gw = gate_w1[c * 32 + jg];
            a0 = fmaf(f_tile[c * 16 + wq], gw, a0);
            a1 = fmaf(f_tile[c * 16 + wq + 8], gw, a1);
        }
        glds[wq * 32 + jg]       = (a0 >= 0.f) ? a0 : 0.2f * a0;
        glds[(wq + 8) * 32 + jg] = (a1 >= 0.f) ? a1 : 0.2f * a1;
    }

    // ---- stage 3: hf[w][j] = f @ w1_f ----
    {
        int j = t & 127, wb = t >> 7;         // wb 0/1 -> w = wb*8 + i
        float acc[8];
        #pragma unroll
        for (int i = 0; i < 8; ++i) acc[i] = 0.f;
        for (int c = 0; c < 128; ++c) {
            float wv = mlp_w1[c * 128 + j];
            const float4* fp = (const float4*)&f_tile[c * 16 + wb * 8];
            float4 fa = fp[0], fb = fp[1];
            acc[0] = fmaf(fa.x, wv, acc[0]);
            acc[1] = fmaf(fa.y, wv, acc[1]);
            acc[2] = fmaf(fa.z, wv, acc[2]);
            acc[3] = fmaf(fa.w, wv, acc[3]);
            acc[4] = fmaf(fb.x, wv, acc[4]);
            acc[5] = fmaf(fb.y, wv, acc[5]);
            acc[6] = fmaf(fb.z, wv, acc[6]);
            acc[7] = fmaf(fb.w, wv, acc[7]);
        }
        #pragma unroll
        for (int i = 0; i < 8; ++i) hf[(wb * 8 + i) * 132 + j] = acc[i];
    }
    __syncthreads();

    // ---- stage 2b: gate = sigmoid(g @ gate_w2 + b2) ----
    if (t < 16) {
        float s = gate_b2[0];
        for (int jg = 0; jg < 32; ++jg) s += glds[t * 32 + jg] * gate_w2[jg];
        gate_s[t] = 1.f / (1.f + expf(-s));
    }

    // ---- stage 4: per (j-chunk, sy): hidden precompute + GEMV tile ----
    for (int chunk = 0; chunk < 2; ++chunk) {
        const int lane_j = chunk * 64 + (t & 63);
        const int wv = t >> 6;                // wave id 0..3
        const int wsb = wv * 16;              // this wave's 16 ws columns
        const float b2v = mlp_b2[lane_j];

        for (int sy = 0; sy < 4; ++sy) {
            __syncthreads();  // hid overwrite vs prior readers (also covers gate_s/glds)
            // phase A: hid[k][ws] = relu(hf[w][k] + hgb[sy*4+sx][k]), ws = w*4+sx
            #pragma unroll 8
            for (int i = 0; i < 32; ++i) {
                int idx = t + i * 256;        // 8192 = 128k * 64ws
                int ws = idx & 63, k = idx >> 6;
                float v = hf[(ws >> 2) * 132 + k] + hgb[((sy << 2) | (ws & 3)) * 132 + k];
                hid[k * 64 + ws] = fmaxf(v, 0.f);
            }
            __syncthreads();

            // phase B: acc[i] = sum_k hid[k][wsb+i] * w2[k][lane_j]
            float acc[16];
            #pragma unroll
            for (int i = 0; i < 16; ++i) acc[i] = 0.f;
            const float* w2p = mlp_w2 + lane_j;
            #pragma unroll 4
            for (int k = 0; k < 128; ++k) {
                float w2v = w2p[(size_t)k * 128];
                const float4* hp = (const float4*)&hid[k * 64 + wsb];
                float4 h0 = hp[0], h1 = hp[1], h2 = hp[2], h3 = hp[3];
                acc[0]  = fmaf(h0.x, w2v, acc[0]);
                acc[1]  = fmaf(h0.y, w2v, acc[1]);
                acc[2]  = fmaf(h0.z, w2v, acc[2]);
                acc[3]  = fmaf(h0.w, w2v, acc[3]);
                acc[4]  = fmaf(h1.x, w2v, acc[4]);
                acc[5]  = fmaf(h1.y, w2v, acc[5]);
                acc[6]  = fmaf(h1.z, w2v, acc[6]);
                acc[7]  = fmaf(h1.w, w2v, acc[7]);
                acc[8]  = fmaf(h2.x, w2v, acc[8]);
                acc[9]  = fmaf(h2.y, w2v, acc[9]);
                acc[10] = fmaf(h2.z, w2v, acc[10]);
                acc[11] = fmaf(h2.w, w2v, acc[11]);
                acc[12] = fmaf(h3.x, w2v, acc[12]);
                acc[13] = fmaf(h3.y, w2v, acc[13]);
                acc[14] = fmaf(h3.z, w2v, acc[14]);
                acc[15] = fmaf(h3.w, w2v, acc[15]);
            }

            // epilogue: out[b][j][h*4+sy][w0*4 + wsb + i] = (acc+b2)*gate[w]
            float g0 = gate_s[wv * 4 + 0];
            float g1 = gate_s[wv * 4 + 1];
            float g2 = gate_s[wv * 4 + 2];
            float g3 = gate_s[wv * 4 + 3];
            float* outp = out + (((size_t)(b * 128 + lane_j) * 256 + (h * 4 + sy)) * 256
                                 + w0 * 4 + wsb);
            float4 o;
            o.x = (acc[0] + b2v) * g0;  o.y = (acc[1] + b2v) * g0;
            o.z = (acc[2] + b2v) * g0;  o.w = (acc[3] + b2v) * g0;
            ((float4*)outp)[0] = o;
            o.x = (acc[4] + b2v) * g1;  o.y = (acc[5] + b2v) * g1;
            o.z = (acc[6] + b2v) * g1;  o.w = (acc[7] + b2v) * g1;
            ((float4*)outp)[1] = o;
            o.x = (acc[8] + b2v) * g2;  o.y = (acc[9] + b2v) * g2;
            o.z = (acc[10] + b2v) * g2; o.w = (acc[11] + b2v) * g2;
            ((float4*)outp)[2] = o;
            o.x = (acc[12] + b2v) * g3; o.y = (acc[13] + b2v) * g3;
            o.z = (acc[14] + b2v) * g3; o.w = (acc[15] + b2v) * g3;
            ((float4*)outp)[3] = o;
        }
    }
}

extern "C" void kernel_launch(void* const* d_in, const int* in_sizes, int n_in,
                              void* d_out, int out_size, void* d_ws, size_t ws_size,
                              hipStream_t stream) {
    const float* feat = (const float*)d_in[0];
    const float* gw1  = (const float*)d_in[1];
    const float* gw2  = (const float*)d_in[2];
    const float* gb2  = (const float*)d_in[3];
    const float* w1   = (const float*)d_in[4];
    const float* b1   = (const float*)d_in[5];
    const float* w2   = (const float*)d_in[6];
    const float* b2   = (const float*)d_in[7];
    float* o = (float*)d_out;

    ipi_kernel<<<dim3(1024), dim3(256), 0, stream>>>(feat, gw1, gw2, gb2, w1, b1, w2, b2, o);
}

// Round 2
// 55.346 us; speedup vs baseline: 3.4547x; 3.4547x over previous
//
#include <hip/hip_runtime.h>
#include <hip/hip_bf16.h>
#include <math.h>

// ImplicitPolygonInjector: B=4, C=128, H=W=64, S=4
// out[b][j][h*4+sy][w*4+sx] = (relu(hf[b,h,w,:] + hg[sy,sx,:] + b1) @ w2 + b2)[j] * gate[b,h,w]
//
// R1: main GEMM on bf16 MFMA (16x16x32), swapped operands: D[j][m] = w2T x hidden^T.
// Pre-kernel transposes w2 -> bf16 w2T in d_ws. Per block: (b,h,16w) -> M=256 rows
// (m = sy*64 + wl*4 + sx), done in two halves of 128 m (32 KB bf16 LDS, XOR-swizzled).

typedef __attribute__((ext_vector_type(8))) short bf16x8;
typedef __attribute__((ext_vector_type(4))) float f32x4;

__device__ inline short f2bf(float v) {
    __hip_bfloat16 b = __float2bfloat16(v);
    return *reinterpret_cast<short*>(&b);
}

__global__ __launch_bounds__(256) void w2t_kernel(const float* __restrict__ w2,
                                                  __hip_bfloat16* __restrict__ w2t) {
    __shared__ float tile[16][17];
    const int kt = (blockIdx.x & 7) * 16, jt = (blockIdx.x >> 3) * 16;
    const int tx = threadIdx.x & 15, ty = threadIdx.x >> 4;
    tile[ty][tx] = w2[(kt + ty) * 128 + jt + tx];
    __syncthreads();
    w2t[(jt + ty) * 128 + kt + tx] = __float2bfloat16(tile[tx][ty]);
}

__global__ __launch_bounds__(256, 3) void ipi_kernel(
    const float* __restrict__ feat,     // (4,128,64,64)
    const float* __restrict__ gate_w1,  // (128,32)
    const float* __restrict__ gate_w2,  // (32,1)
    const float* __restrict__ gate_b2,  // (1,)
    const float* __restrict__ mlp_w1,   // (130,128)
    const float* __restrict__ mlp_b1,   // (128,)
    const float* __restrict__ mlp_b2,   // (128,)
    const __hip_bfloat16* __restrict__ w2t,  // (128j,128k) bf16
    float* __restrict__ out)            // (4,128,256,256)
{
    __shared__ float hf[16 * 132];      // hf[w][j], fp32
    __shared__ float hgb[16 * 132];     // hgb[s][k] = h_g + b1, fp32
    __shared__ float gate_s[16];
    __shared__ char  hid[32768];        // hidden bf16 [128 m][128 k], XOR-swizzled
    float* f_tile = (float*)hid;        // [128 c][16 w], dead before phase A
    float* glds   = (float*)(hid + 8192); // [16 w][32 jg], dead before phase A

    const int t    = threadIdx.x;
    const int lane = t & 63;
    const int wv   = t >> 6;            // wave id 0..3 -> j-range wv*32..+31
    const int bx   = blockIdx.x;
    const int w0   = (bx & 3) * 16;
    const int h    = (bx >> 2) & 63;
    const int b    = bx >> 8;

    // ---- A-fragments (w2T) + b2 into registers: global only, no LDS dep ----
    bf16x8 afrag[2][4];
    f32x4  b2v[2];
    {
        const __hip_bfloat16* base = w2t + (wv * 32 + (lane & 15)) * 128 + (lane >> 4) * 8;
        #pragma unroll
        for (int jt = 0; jt < 2; ++jt) {
            #pragma unroll
            for (int ks = 0; ks < 4; ++ks)
                afrag[jt][ks] = *(const bf16x8*)(base + jt * 16 * 128 + ks * 32);
            b2v[jt] = *(const f32x4*)&mlp_b2[wv * 32 + jt * 16 + (lane >> 4) * 4];
        }
    }

    // ---- stage 0: f tile [c][w] + hgb[s][k] ----
    {
        const float* fbase = feat + ((size_t)(b * 128) * 64 + h) * 64 + w0;
        #pragma unroll
        for (int i = 0; i < 8; ++i) {
            int idx = t + i * 256;            // 2048 = 128c * 16w
            int c = idx >> 4, w = idx & 15;
            f_tile[c * 16 + w] = fbase[(size_t)c * 4096 + w];
        }
        #pragma unroll
        for (int i = 0; i < 8; ++i) {
            int idx = t + i * 256;            // 2048 = 16s * 128k
            int s = idx >> 7, k = idx & 127;
            float cx = -0.75f + 0.5f * (float)(s & 3);   // coords[sx]
            float cy = -0.75f + 0.5f * (float)(s >> 2);  // coords[sy]
            hgb[s * 132 + k] = cx * mlp_w1[128 * 128 + k]
                             + cy * mlp_w1[129 * 128 + k]
                             + mlp_b1[k];
        }
    }
    __syncthreads();

    // ---- stage 2a: gate hidden g = leaky(f @ gate_w1) ----
    {
        int jg = t & 31, wq = t >> 5;
        float a0 = 0.f, a1 = 0.f;
        for (int c = 0; c < 128; ++c) {
            float gw = gate_w1[c * 32 + jg];
            a0 = fmaf(f_tile[c * 16 + wq], gw, a0);
            a1 = fmaf(f_tile[c * 16 + wq + 8], gw, a1);
        }
        glds[wq * 32 + jg]       = (a0 >= 0.f) ? a0 : 0.2f * a0;
        glds[(wq + 8) * 32 + jg] = (a1 >= 0.f) ? a1 : 0.2f * a1;
    }

    // ---- stage 3: hf[w][j] = f @ w1_f (fp32) ----
    {
        int j = t & 127, wb = t >> 7;
        float acc[8];
        #pragma unroll
        for (int i = 0; i < 8; ++i) acc[i] = 0.f;
        for (int c = 0; c < 128; ++c) {
            float wvv = mlp_w1[c * 128 + j];
            const float4* fp = (const float4*)&f_tile[c * 16 + wb * 8];
            float4 fa = fp[0], fb = fp[1];
            acc[0] = fmaf(fa.x, wvv, acc[0]);
            acc[1] = fmaf(fa.y, wvv, acc[1]);
            acc[2] = fmaf(fa.z, wvv, acc[2]);
            acc[3] = fmaf(fa.w, wvv, acc[3]);
            acc[4] = fmaf(fb.x, wvv, acc[4]);
            acc[5] = fmaf(fb.y, wvv, acc[5]);
            acc[6] = fmaf(fb.z, wvv, acc[6]);
            acc[7] = fmaf(fb.w, wvv, acc[7]);
        }
        #pragma unroll
        for (int i = 0; i < 8; ++i) hf[(wb * 8 + i) * 132 + j] = acc[i];
    }
    __syncthreads();

    // ---- stage 2b: gate = sigmoid(g @ gate_w2 + b2) ----
    if (t < 16) {
        float s = gate_b2[0];
        for (int jg = 0; jg < 32; ++jg) s += glds[t * 32 + jg] * gate_w2[jg];
        gate_s[t] = 1.f / (1.f + expf(-s));
    }

    // ---- halves: 128 m each (m = half*128 + mh) ----
    for (int half = 0; half < 2; ++half) {
        __syncthreads();  // prior readers of hid region / gate_s ordering

        // phase A: hid[mh][k] = bf16(relu(hf[w][k] + hgb[s][k]))
        {
            const int mh = t >> 1;
            const int w  = (mh >> 2) & 15;
            const int s  = ((((half << 7) + mh) >> 6) << 2) | (mh & 3);
            const float* hfr = hf  + w * 132 + (t & 1) * 64;
            const float* hgr = hgb + s * 132 + (t & 1) * 64;
            char* rowp = hid + mh * 256;
            const int kb0 = (t & 1) * 128;            // byte offset of k-half
            const int sw  = (mh & 7) << 4;
            #pragma unroll
            for (int kc = 0; kc < 8; ++kc) {
                float4 a0 = *(const float4*)(hfr + kc * 8);
                float4 a1 = *(const float4*)(hfr + kc * 8 + 4);
                float4 g0 = *(const float4*)(hgr + kc * 8);
                float4 g1 = *(const float4*)(hgr + kc * 8 + 4);
                bf16x8 hv;
                hv[0] = f2bf(fmaxf(a0.x + g0.x, 0.f));
                hv[1] = f2bf(fmaxf(a0.y + g0.y, 0.f));
                hv[2] = f2bf(fmaxf(a0.z + g0.z, 0.f));
                hv[3] = f2bf(fmaxf(a0.w + g0.w, 0.f));
                hv[4] = f2bf(fmaxf(a1.x + g1.x, 0.f));
                hv[5] = f2bf(fmaxf(a1.y + g1.y, 0.f));
                hv[6] = f2bf(fmaxf(a1.z + g1.z, 0.f));
                hv[7] = f2bf(fmaxf(a1.w + g1.w, 0.f));
                *(bf16x8*)(rowp + ((kb0 + kc * 16) ^ sw)) = hv;
            }
        }
        __syncthreads();

        // phase B: per wave, D[j 32][m 128] via MFMA; store with bias+gate
        for (int mt = 0; mt < 8; ++mt) {
            const int mrow = mt * 16 + (lane & 15);
            const int swb  = (mrow & 7) << 4;
            const char* rowp = hid + mrow * 256;
            bf16x8 bfrag[4];
            #pragma unroll
            for (int ks = 0; ks < 4; ++ks)
                bfrag[ks] = *(const bf16x8*)(rowp + ((ks * 64 + (lane >> 4) * 16) ^ swb));

            f32x4 acc0 = {0.f, 0.f, 0.f, 0.f};
            f32x4 acc1 = {0.f, 0.f, 0.f, 0.f};
            #pragma unroll
            for (int ks = 0; ks < 4; ++ks) {
                acc0 = __builtin_amdgcn_mfma_f32_16x16x32_bf16(afrag[0][ks], bfrag[ks], acc0, 0, 0, 0);
                acc1 = __builtin_amdgcn_mfma_f32_16x16x32_bf16(afrag[1][ks], bfrag[ks], acc1, 0, 0, 0);
            }

            const int m  = (half << 7) + mrow;
            const int sy = m >> 6;
            const float g = gate_s[(m >> 2) & 15];
            float* outp = out + ((size_t)(b * 128 + wv * 32 + (lane >> 4) * 4) << 16)
                              + (size_t)(h * 4 + sy) * 256 + w0 * 4 + (m & 63);
            #pragma unroll
            for (int r = 0; r < 4; ++r) {
                outp[(size_t)r << 16]        = (acc0[r] + b2v[0][r]) * g;
                outp[(size_t)(r + 16) << 16] = (acc1[r] + b2v[1][r]) * g;
            }
        }
    }
}

extern "C" void kernel_launch(void* const* d_in, const int* in_sizes, int n_in,
                              void* d_out, int out_size, void* d_ws, size_t ws_size,
                              hipStream_t stream) {
    const float* feat = (const float*)d_in[0];
    const float* gw1  = (const float*)d_in[1];
    const float* gw2  = (const float*)d_in[2];
    const float* gb2  = (const float*)d_in[3];
    const float* w1   = (const float*)d_in[4];
    const float* b1   = (const float*)d_in[5];
    const float* w2   = (const float*)d_in[6];
    const float* b2   = (const float*)d_in[7];
    float* o = (float*)d_out;
    __hip_bfloat16* w2t = (__hip_bfloat16*)d_ws;   // 128*128*2 = 32 KB

    w2t_kernel<<<dim3(64), dim3(256), 0, stream>>>(w2, w2t);
    ipi_kernel<<<dim3(1024), dim3(256), 0, stream>>>(feat, gw1, gw2, gb2, w1, b1, b2, w2t, o);
}